// Round 11
// baseline (153.063 us; speedup 1.0000x reference)
//
#include <hip/hip_runtime.h>
#include <hip/hip_bf16.h>

// Problem constants (B,H,W,C = 32,32,32,256 -> l = 1024)
#define BATCH 32
#define L 1024
#define CD 256

typedef __bf16 bf16x8 __attribute__((ext_vector_type(8)));
typedef float  f32x4  __attribute__((ext_vector_type(4)));
typedef unsigned long long u64;

__device__ __forceinline__ unsigned int enc_f32(float f) {
    unsigned int u = __float_as_uint(f);
    return ((int)u < 0) ? ~u : (u | 0x80000000u);
}
__device__ __forceinline__ float dec_f32(unsigned int u) {
    u = (u & 0x80000000u) ? (u & 0x7FFFFFFFu) : ~u;
    return __uint_as_float(u);
}
__device__ __forceinline__ u64 pmax(u64 a, u64 b) { return a > b ? a : b; }
__device__ __forceinline__ bf16x8 cvt8(float4 a, float4 b) {
    bf16x8 o;
    o[0] = (__bf16)a.x; o[1] = (__bf16)a.y; o[2] = (__bf16)a.z; o[3] = (__bf16)a.w;
    o[4] = (__bf16)b.x; o[5] = (__bf16)b.y; o[6] = (__bf16)b.z; o[7] = (__bf16)b.w;
    return o;
}

// Kernel 0: fp32 -> bf16 cast + permute into FRAGMENT-ORDER global layouts so
// the matmul loads MFMA operands directly from global with one coalesced
// global_load_dwordx4 per fragment (no LDS, no swizzle needed — r10 lesson:
// every LDS-staged barrier-cycle structure plateaus at ~55us with all pipes
// <35%; the barrier produce/consume cycle IS the bottleneck).
// Fragment (16x16x32 bf16): lane(q=lane>>4, l=lane&15) holds elem
// [row/col = l][k = q*8 .. q*8+7], i.e. 16 contiguous B per lane.
//  pT (A/preds) chunk index  ((b*32 + rw)*16 + f)*64 + lane,
//     rw = rowblock/32 (rt*2+wm), f = tm*8 + kf: row = rw*32+tm*16+l, k = kf*32+q*8
//  qT (B/queries) chunk index ((b*64 + cf)*8 + kf)*64 + lane,
//     cf = col/16: col = cf*16+l, k = kf*32+q*8
// One thread = one 16B output chunk (reads 32B fp32).
__global__ __launch_bounds__(256) void convert_kernel(
    const float* __restrict__ qg,   // feats1 [B][L][CD] (queries)
    const float* __restrict__ pg,   // feats2 [B][L][CD] (preds)
    __bf16* __restrict__ qT,
    __bf16* __restrict__ pT)
{
    const unsigned int t = blockIdx.x * 256 + threadIdx.x;   // 0..2M-1
    const unsigned int v = t & 0xFFFFFu;
    const int lane = v & 63;
    const int l    = lane & 15;
    const int q    = lane >> 4;
    const float* src;
    __bf16* dst;
    if (t >> 20) {   // Q fragments
        const int kf = (v >> 6) & 7;
        const int cf = (v >> 9) & 63;
        const int b  = v >> 15;
        src = qg + ((size_t)(b << 10) + (cf << 4) + l) * CD + (kf << 5) + (q << 3);
        dst = qT + (size_t)v * 8;
    } else {         // P fragments
        const int f  = (v >> 6) & 15;
        const int rw = (v >> 10) & 31;
        const int b  = v >> 15;
        const int row = (rw << 5) + ((f >> 3) << 4) + l;
        src = pg + ((size_t)(b << 10) + row) * CD + ((f & 7) << 5) + (q << 3);
        dst = pT + (size_t)v * 8;
    }
    const float4 f0 = ((const float4*)src)[0];
    const float4 f1 = ((const float4*)src)[1];
    *(bf16x8*)dst = cvt8(f0, f1);
}

// Kernel 1: BARRIER-FREE matmul+argmax. 512 blocks (32 b x 16 rt of 64 rows),
// 512 thr = 8 waves (2 wm x 4 wn). Each wave: 32 rows x 256 cols, fully
// independent — no LDS for matrices, no s_barrier in the loop.
// A: 16 frags -> registers (64 VGPR; the 128-cap-safe size, unlike r5/7/8's
// 32-frag spill). B: per col-tile (32 cols), 16 coalesced frag loads straight
// from L2/L3-resident qT, 32 MFMAs, in-register argmax. 4 waves/SIMD
// (VGPR ~128 -> 16 waves/CU) hide L2 latency wave-to-wave; floor = L1
// fragment delivery (~2 MB/CU).
__global__ __launch_bounds__(512) void mm_argmax_kernel(
    const __bf16* __restrict__ qT,
    const __bf16* __restrict__ pT,
    u64* __restrict__ colpart,   // [B][32][L] (enc(val)<<32)|~a
    int* __restrict__ max2)      // [B][L]
{
    __shared__ u64 sRow[4][64];  // 2 KB, used once at the end

    const int tid = threadIdx.x;
    const int bid = blockIdx.x;
    // bid = rt*32 + b -> XCD = b%8 sticky; co-resident blocks share batch data.
    const int b  = bid & 31;
    const int rt = bid >> 5;

    const int lane = tid & 63;
    const int w    = tid >> 6;
    const int wm   = w >> 2;      // 0..1: rows wm*32
    const int wn   = w & 3;       // 0..3: cols wn*256
    const int quad = lane >> 4;
    const int l16  = lane & 15;

    // ---- A fragments -> registers: 16 x bf16x8 = 64 VGPR, coalesced ----
    const __bf16* pA = pT + (size_t)((b * 32 + rt * 2 + wm) * 16) * 512;
    bf16x8 afr[16];
    #pragma unroll
    for (int f = 0; f < 16; ++f)
        afr[f] = *(const bf16x8*)&pA[(size_t)(f * 64 + lane) * 8];

    const __bf16* pB = qT + (size_t)b * (64 * 8 * 512);

    f32x4 acc[2][2];
    u64 rowbest[2][4];
    #pragma unroll
    for (int tm = 0; tm < 2; ++tm)
        #pragma unroll
        for (int r = 0; r < 4; ++r) rowbest[tm][r] = 0ull;

    const int a0q = rt * 64 + wm * 32 + quad * 4;          // + tm*16 + r
    const size_t colbase = ((size_t)b * 32 + rt * 2 + wm) * L;

    for (int t = 0; t < 8; ++t) {
        const int cf0 = wn * 16 + t * 2;                   // 16-col frag index
        const __bf16* pBt = pB + (size_t)cf0 * (8 * 512);

        #pragma unroll
        for (int tm = 0; tm < 2; ++tm)
            #pragma unroll
            for (int tn = 0; tn < 2; ++tn) acc[tm][tn] = (f32x4){0.f, 0.f, 0.f, 0.f};

        #pragma unroll
        for (int kf = 0; kf < 8; ++kf) {
            bf16x8 b0 = *(const bf16x8*)&pBt[(size_t)(kf * 64 + lane) * 8];
            bf16x8 b1 = *(const bf16x8*)&pBt[(size_t)((8 + kf) * 64 + lane) * 8];
            acc[0][0] = __builtin_amdgcn_mfma_f32_16x16x32_bf16(afr[kf],     b0, acc[0][0], 0, 0, 0);
            acc[0][1] = __builtin_amdgcn_mfma_f32_16x16x32_bf16(afr[kf],     b1, acc[0][1], 0, 0, 0);
            acc[1][0] = __builtin_amdgcn_mfma_f32_16x16x32_bf16(afr[8 + kf], b0, acc[1][0], 0, 0, 0);
            acc[1][1] = __builtin_amdgcn_mfma_f32_16x16x32_bf16(afr[8 + kf], b1, acc[1][1], 0, 0, 0);
        }

        // row running argmax (j ascends with t,tn; pmax on ~j = first index)
        const int jb = wn * 256 + t * 32 + l16;
        #pragma unroll
        for (int tm = 0; tm < 2; ++tm)
            #pragma unroll
            for (int r = 0; r < 4; ++r)
                #pragma unroll
                for (int tn = 0; tn < 2; ++tn) {
                    const u64 pk = ((u64)enc_f32(acc[tm][tn][r]) << 32)
                                 | (unsigned int)(~(unsigned int)(jb + tn * 16));
                    rowbest[tm][r] = pmax(rowbest[tm][r], pk);
                }

        // col argmax over the wave's 32 rows (ascending a scan in-lane, then
        // quad combine), straight to global partials — no LDS, no barrier.
        #pragma unroll
        for (int tn = 0; tn < 2; ++tn) {
            float cv = acc[0][tn][0];
            int   ca = a0q;
            #pragma unroll
            for (int tm = 0; tm < 2; ++tm)
                #pragma unroll
                for (int r = 0; r < 4; ++r) {
                    if (tm == 0 && r == 0) continue;
                    if (acc[tm][tn][r] > cv) { cv = acc[tm][tn][r]; ca = a0q + tm * 16 + r; }
                }
            u64 pk = ((u64)enc_f32(cv) << 32) | (unsigned int)(~(unsigned int)ca);
            pk = pmax(pk, __shfl_xor(pk, 16));
            pk = pmax(pk, __shfl_xor(pk, 32));
            if (quad == 0)
                colpart[colbase + wn * 256 + t * 32 + tn * 16 + l16] = pk;
        }
    }

    // ---- row argmax finish: reduce over l16 lanes, combine 4 wn via LDS ----
    #pragma unroll
    for (int tm = 0; tm < 2; ++tm)
        #pragma unroll
        for (int r = 0; r < 4; ++r) {
            u64 pk = rowbest[tm][r];
            pk = pmax(pk, __shfl_xor(pk, 1));
            pk = pmax(pk, __shfl_xor(pk, 2));
            pk = pmax(pk, __shfl_xor(pk, 4));
            pk = pmax(pk, __shfl_xor(pk, 8));
            if (l16 == 0) sRow[wn][wm * 32 + tm * 16 + quad * 4 + r] = pk;
        }
    __syncthreads();
    if (tid < 64) {
        const u64 m = pmax(pmax(sRow[0][tid], sRow[1][tid]),
                           pmax(sRow[2][tid], sRow[3][tid]));
        max2[(size_t)b * L + rt * 64 + tid] = (int)(~(unsigned int)m) & (L - 1);
    }
}

// Kernel 2: reduce col partials (32-deep: rt x wm) + mutual-NN + mean.
__global__ __launch_bounds__(1024) void finalize_kernel(
    const u64* __restrict__ colpart,  // [B][32][L]
    const int* __restrict__ max2,     // [B][L]
    float* __restrict__ out)
{
    __shared__ int sMax2[L];
    __shared__ float sSum[16];
    __shared__ int sCnt[16];
    const int b = blockIdx.x;
    const int j = threadIdx.x;        // 0..1023

    sMax2[j] = max2[(size_t)b * L + j];

    u64 cb = 0ull;
    #pragma unroll
    for (int k = 0; k < 32; ++k)
        cb = pmax(cb, colpart[((size_t)b * 32 + k) * L + j]);
    __syncthreads();

    const int a = (int)(~(unsigned int)cb) & (L - 1);      // max1[j]
    const float val = dec_f32((unsigned int)(cb >> 32));   // sims[j]
    const bool mut = (sMax2[a] == j);                      // mutual NN
    float sum = mut ? val : 0.f;
    int   cnt = mut ? 1 : 0;

    #pragma unroll
    for (int o = 32; o >= 1; o >>= 1) {
        sum += __shfl_down(sum, o);
        cnt += __shfl_down(cnt, o);
    }
    if ((j & 63) == 0) { sSum[j >> 6] = sum; sCnt[j >> 6] = cnt; }
    __syncthreads();
    if (j == 0) {
        float S = 0.f;
        int   C = 0;
        #pragma unroll
        for (int i = 0; i < 16; ++i) { S += sSum[i]; C += sCnt[i]; }
        out[b] = S / fmaxf((float)C, 1.0f);
    }
}

extern "C" void kernel_launch(void* const* d_in, const int* in_sizes, int n_in,
                              void* d_out, int out_size, void* d_ws, size_t ws_size,
                              hipStream_t stream) {
    const float* q = (const float*)d_in[0];   // feats1 (queries)
    const float* p = (const float*)d_in[1];   // feats2 (preds)
    float* out = (float*)d_out;

    // ws layout: colpart [32][32][1024] u64 (8 MiB) | max2 [32][1024] int
    // (128 KiB, padded to 512 KiB) | pT bf16 (16 MiB) | qT bf16 (16 MiB).
    // Every slot written before read -> no init needed.
    u64* colpart = (u64*)d_ws;
    int* max2 = (int*)(colpart + (size_t)BATCH * 32 * L);
    __bf16* pT = (__bf16*)((char*)d_ws + (8u << 20) + (512u << 10));
    __bf16* qT = pT + (size_t)8388608;

    convert_kernel<<<8192, 256, 0, stream>>>(q, p, qT, pT);
    mm_argmax_kernel<<<BATCH * 16, 512, 0, stream>>>(qT, pT, colpart, max2);
    finalize_kernel<<<BATCH, 1024, 0, stream>>>(colpart, max2, out);
}